// Round 1
// 115.257 us; speedup vs baseline: 1.0361x; 1.0361x over previous
//
#include <hip/hip_runtime.h>
#include <math.h>

#define NB   4      // n
#define C    128    // channels
#define S    31     // frames
#define HW   704    // h*w = 32*22
#define T    30     // s-1
#define NS   120    // n*(s-1)
#define K    16     // top_k

// ---------------------------------------------------------------------------
// Kernel 1: 1x1 conv (C->1), float4-vectorized. Each lane owns one float4
// (4 consecutive pixels); wave = 256 contiguous pixels; 4 waves/block = 4
// channel-groups of 32, LDS combine. 341 blocks x 4 waves = 1364 waves
// (~5.3/SIMD). 16B/lane loads (global_load_dwordx4) -> BW floor ~7.2 us.
// ---------------------------------------------------------------------------
__global__ __launch_bounds__(256) void conv_kernel(
    const float* __restrict__ x,
    const float* __restrict__ w1, const float* __restrict__ b1p,
    const float* __restrict__ w2, const float* __restrict__ b2p,
    float* __restrict__ A, float* __restrict__ B) {
  const int tid  = threadIdx.x;
  const int lane = tid & 63;
  const int cg   = tid >> 6;                 // wave-uniform channel group
  const int g    = blockIdx.x * 64 + lane;   // float4 index, 0..21823
  const int fr   = g / 176;                  // (n, sf), 176 float4s per frame
  const int f4   = g % 176;
  const int sf   = fr % S;
  const int n    = fr / S;

  const float4* xp =
      (const float4*)(x + (((size_t)(n * C + cg * 32) * S + sf) * HW)) + f4;
  float4 a1 = make_float4(0.f, 0.f, 0.f, 0.f);
  float4 a2 = make_float4(0.f, 0.f, 0.f, 0.f);
#pragma unroll
  for (int c = 0; c < 32; ++c) {
    float4 xv = xp[(size_t)c * (S * HW / 4)];
    const float wa = w1[cg * 32 + c];        // wave-uniform -> s_load
    const float wb = w2[cg * 32 + c];
    a1.x = fmaf(xv.x, wa, a1.x); a1.y = fmaf(xv.y, wa, a1.y);
    a1.z = fmaf(xv.z, wa, a1.z); a1.w = fmaf(xv.w, wa, a1.w);
    a2.x = fmaf(xv.x, wb, a2.x); a2.y = fmaf(xv.y, wb, a2.y);
    a2.z = fmaf(xv.z, wb, a2.z); a2.w = fmaf(xv.w, wb, a2.w);
  }
  __shared__ float4 s1[4][64];
  __shared__ float4 s2[4][64];
  s1[cg][lane] = a1;
  s2[cg][lane] = a2;
  __syncthreads();
  if (tid < 64) {
    float4 r1 = s1[0][tid], r2 = s2[0][tid];
#pragma unroll
    for (int u = 1; u < 4; ++u) {
      float4 t1 = s1[u][tid], t2 = s2[u][tid];
      r1.x += t1.x; r1.y += t1.y; r1.z += t1.z; r1.w += t1.w;
      r2.x += t2.x; r2.y += t2.y; r2.z += t2.z; r2.w += t2.w;
    }
    const float bb1 = b1p[0], bb2 = b2p[0];
    r1.x += bb1; r1.y += bb1; r1.z += bb1; r1.w += bb1;
    r2.x += bb2; r2.y += bb2; r2.z += bb2; r2.w += bb2;
    if (sf < T)
      ((float4*)(A + (size_t)(n * T + sf) * HW))[f4] = r1;
    if (sf >= 1)
      ((float4*)(B + (size_t)(n * T + sf - 1) * HW))[f4] = r2;
  }
}

// ---------------------------------------------------------------------------
// Kernel 2 (REPLACED bitonic sort): wave-parallel 16-round max/min
// extraction. One 64-lane wave per frame pair; 704 = 11*64 values live in
// registers (11/lane, static indices only -> no scratch). Per round:
//   local fmax/fmin scan (11 ops) -> 6-stage shfl_xor butterfly ->
//   ballot-picked owner lane clears exactly ONE instance (duplicate-safe).
// Top and bottom rounds interleaved: two independent shuffle chains overlap,
// VALU scans fill shuffle latency. ~3k cycles/wave, 120 parallel waves,
// no LDS, no barriers (vs 55 barrier-serialized bitonic passes ~7-11 us).
// Round r emits the r-th largest (btop desc) / r-th smallest (bbot asc),
// matching the old sort kernel's output layout exactly.
// ---------------------------------------------------------------------------
__global__ __launch_bounds__(64) void select_kernel(
    const float* __restrict__ B,
    float* __restrict__ btop, float* __restrict__ bbot) {
  const int i    = blockIdx.x;
  const int lane = threadIdx.x;
  const float* __restrict__ bi = B + i * HW;

  float vt[11], vb[11];
#pragma unroll
  for (int j = 0; j < 11; ++j) {
    const float v = bi[j * 64 + lane];
    vt[j] = v;
    vb[j] = v;
  }

#pragma unroll 1
  for (int r = 0; r < K; ++r) {
    // local extrema over the 11 register slots (all static indices)
    float lmT = vt[0], lmB = vb[0];
#pragma unroll
    for (int j = 1; j < 11; ++j) {
      lmT = fmaxf(lmT, vt[j]);
      lmB = fminf(lmB, vb[j]);
    }
    // wave-wide extrema: two independent 6-stage butterflies
    float gT = lmT, gB = lmB;
#pragma unroll
    for (int off = 1; off < 64; off <<= 1) {
      gT = fmaxf(gT, __shfl_xor(gT, off, 64));
      gB = fminf(gB, __shfl_xor(gB, off, 64));
    }
    // exactly one lane clears exactly one matching slot (dup-safe)
    const unsigned long long mT = __ballot(lmT == gT);
    const unsigned long long mB = __ballot(lmB == gB);
    if (lane == (int)(__ffsll(mT) - 1)) {
      bool done = false;
#pragma unroll
      for (int j = 0; j < 11; ++j) {
        const bool hit = (!done) && (vt[j] == gT);
        vt[j] = hit ? -INFINITY : vt[j];
        done  = done || hit;
      }
    }
    if (lane == (int)(__ffsll(mB) - 1)) {
      bool done = false;
#pragma unroll
      for (int j = 0; j < 11; ++j) {
        const bool hit = (!done) && (vb[j] == gB);
        vb[j] = hit ? INFINITY : vb[j];
        done  = done || hit;
      }
    }
    if (lane == 0) {
      btop[i * K + r] = gT;  // r-th largest  -> descending
      bbot[i * K + r] = gB;  // r-th smallest -> ascending
    }
  }
}

// ---------------------------------------------------------------------------
// Kernel 3: one wave per FOUR rows of the same frame pair (r, r+176, r+352,
// r+528). 21120 waves, 5280 blocks (~20 waves/CU TLP). Each b element
// loaded once feeds 4 exps (L2 re-read quartered to ~60 MB, 4-way ILP on
// the exp chain, quarter the butterfly work). Lane l covers q = j*64+l
// (coalesced). ln2 folded into the fma -> raw v_exp_f32. m = exact row max
// of a*b so every exponent <= 0; a==0 -> uniform 1/704 automatically.
// Output raw-reshape: row r -> (j_out=r/44, p_out=(r%44)*16), 16 contiguous
// floats per row.
// ---------------------------------------------------------------------------
__global__ __launch_bounds__(256) void softmax_topk_kernel(
    const float* __restrict__ A, const float* __restrict__ B,
    const float* __restrict__ btop, const float* __restrict__ bbot,
    float* __restrict__ out) {
  const int lane = threadIdx.x & 63;
  const int wid  = blockIdx.x * 4 + (threadIdx.x >> 6);  // 0..21119
  const int i    = wid / 176;                            // frame pair
  const int rb   = wid % 176;                            // base row

  const float st0 = btop[i * K];
  const float sb0 = bbot[i * K];
  const float L2E = 1.4426950408889634f;
  float av[4], a2[4], nm[4], part[4];
#pragma unroll
  for (int u = 0; u < 4; ++u) {
    av[u]   = A[i * HW + rb + u * 176];
    a2[u]   = av[u] * L2E;
    nm[u]   = -((av[u] >= 0.f) ? av[u] * st0 : av[u] * sb0) * L2E;
    part[u] = 0.f;
  }

  const float* __restrict__ bi = B + i * HW;
#pragma unroll
  for (int j = 0; j < 11; ++j) {
    const float bv = bi[j * 64 + lane];
#pragma unroll
    for (int u = 0; u < 4; ++u)
      part[u] += __builtin_amdgcn_exp2f(fmaf(a2[u], bv, nm[u]));
  }
#pragma unroll
  for (int off = 1; off < 64; off <<= 1) {
#pragma unroll
    for (int u = 0; u < 4; ++u)
      part[u] += __shfl_xor(part[u], off, 64);
  }

  if (lane < K) {
    const int n  = i / T;
    const int t  = i % T;
    float* obase = out + (((size_t)n * K) * T + t) * HW;
    const float tv = btop[i * K + lane];
    const float bv = bbot[i * K + lane];
#pragma unroll
    for (int u = 0; u < 4; ++u) {
      const int r = rb + u * 176;
      const float sel = (av[u] >= 0.f) ? tv : bv;
      const float val = __builtin_amdgcn_exp2f(fmaf(a2[u], sel, nm[u])) / part[u];
      obase[(size_t)(r / 44) * (T * HW) + (r % 44) * K + lane] = val;
    }
  }
}

extern "C" void kernel_launch(void* const* d_in, const int* in_sizes, int n_in,
                              void* d_out, int out_size, void* d_ws, size_t ws_size,
                              hipStream_t stream) {
  (void)in_sizes; (void)n_in; (void)out_size; (void)ws_size;
  const float* x  = (const float*)d_in[0];
  const float* w1 = (const float*)d_in[1];
  const float* b1 = (const float*)d_in[2];
  const float* w2 = (const float*)d_in[3];
  const float* b2 = (const float*)d_in[4];
  // d_in[5] is top_k (=16), hardcoded as K.
  float* out = (float*)d_out;

  float* A    = (float*)d_ws;            // NS*HW
  float* B    = A + NS * HW;             // NS*HW
  float* btop = B + NS * HW;             // NS*K
  float* bbot = btop + NS * K;           // NS*K

  conv_kernel<<<341, 256, 0, stream>>>(x, w1, b1, w2, b2, A, B);
  select_kernel<<<NS, 64, 0, stream>>>(B, btop, bbot);
  softmax_topk_kernel<<<5280, 256, 0, stream>>>(A, B, btop, bbot, out);
}